// Round 16
// baseline (68.682 us; speedup 1.0000x reference)
//
#include <hip/hip_runtime.h>
#include <hip/hip_bf16.h>
#include <math.h>
#include <utility>

#define K_COMP 64
#define D 32
#define NTRIL 496
#define ICF_COLS 528
#define NPAIR 528            // i<=j pairs
#define NFEAT 560            // 32 linear + 528 pair (constant term in epilogue)
#define NCHUNK 18            // 576 = 18*32 padded features
#define PTS_PER_BLK 32
#define ROWB 1168            // phi row stride bytes
#define XSTRIDE 33           // xs row stride floats: 33 mod 32 = 1 -> conflict-free rows

typedef __attribute__((ext_vector_type(8))) short v8s;
typedef __attribute__((ext_vector_type(4))) float v4f;

__device__ __forceinline__ unsigned short f2bf(float f) {
  unsigned int u = __float_as_uint(f);
  unsigned int r = (u + 0x7FFFu + ((u >> 16) & 1u)) >> 16;
  return (unsigned short)r;
}
__device__ __forceinline__ v8s asv8(int4 v) {
  union { int4 i; v8s s; } u; u.i = v; return u.s;
}

// pair enumeration t -> (i,j), i<=j, i ascending, j from i..31
constexpr int pr_i(int t) { int i = 0; while (t >= D - i) { t -= D - i; ++i; } return i; }
constexpr int pr_j(int t) { int i = 0; while (t >= D - i) { t -= D - i; ++i; } return i + t; }

// feature read DIRECTLY from LDS row (compile-time offsets; no register array)
template<int F> __device__ __forceinline__ float featL(const float* __restrict__ xrow) {
  if constexpr (F < 32) return xrow[F];
  else if constexpr (F < NFEAT) {
    constexpr int t = F - 32, i = pr_i(t), j = pr_j(t);
    return xrow[i] * xrow[j];
  } else return 0.0f;
}

// 4 features -> 2x v_cvt_pk_bf16_f32 -> one 8B LDS write
template<int F0> __device__ __forceinline__ void write4L(const float* __restrict__ xrow, char* row) {
  __hip_bfloat162 pa = __float22bfloat162_rn(make_float2(featL<F0+0>(xrow), featL<F0+1>(xrow)));
  __hip_bfloat162 pb = __float22bfloat162_rn(make_float2(featL<F0+2>(xrow), featL<F0+3>(xrow)));
  union { __hip_bfloat162 h2; unsigned u; } ua, ub;
  ua.h2 = pa; ub.h2 = pb;
  *reinterpret_cast<uint2*>(row + (size_t)F0 * 2) = make_uint2(ua.u, ub.u);
}
template<int BASE, size_t... Qs> __device__ __forceinline__
void gen72(const float* __restrict__ xrow, char* row, std::index_sequence<Qs...>) {
  (write4L<BASE + 4 * (int)Qs>(xrow, row), ...);
}

// ------------------- prep: one block per component k; block 0 also builds tail_const ----
__global__ __launch_bounds__(64) void gmm_prep(
    const float* __restrict__ alphas, const float* __restrict__ means,
    const float* __restrict__ icf, const float* __restrict__ wg,
    const float* __restrict__ wm, int N,
    uint4* __restrict__ Whi, float* __restrict__ eSa, float* __restrict__ wwk,
    double* __restrict__ tailc)
{
  int k = blockIdx.x;
  int l = threadIdx.x;
  __shared__ float M[D][D + 1];
  __shared__ float mu[D], b[D], v[D];
  __shared__ float At[NPAIR];
  __shared__ float red[64];

  const float* ick = icf + (size_t)k * ICF_COLS;

  if (l < D) {
    mu[l] = means[k * D + l];
    float q = __expf(ick[l]);
    for (int c = 0; c < D; ++c) {
      float val;
      if (c < l) { int off = c * 31 - c * (c - 1) / 2; val = ick[D + off + (l - c - 1)]; }
      else if (c == l) val = q;
      else val = 0.0f;
      M[l][c] = val;
    }
  }
  __syncthreads();
  if (l < D) {
    float acc = 0.f;
    for (int c = 0; c < D; ++c) acc = fmaf(M[l][c], mu[c], acc);
    b[l] = acc;
  }
  __syncthreads();
  if (l < D) {
    float acc = 0.f;
    for (int r = 0; r < D; ++r) acc = fmaf(M[r][l], b[r], acc);
    v[l] = acc;
  }
  for (int t = l; t < NPAIR; t += 64) {
    int tt = t, i = 0;
    while (tt >= D - i) { tt -= D - i; ++i; }
    int j = i + tt;
    float acc = 0.f;
    for (int r = 0; r < D; ++r) acc = fmaf(M[r][i], M[r][j], acc);
    At[t] = (i == j) ? -0.5f * acc : -acc;
  }
  float part = 0.f;
  for (int e = l; e < D * D; e += 64) {
    float mv = M[e / D][e % D];
    part = fmaf(mv, mv, part);
  }
  red[l] = part;
  __syncthreads();
  for (int st = 32; st > 0; st >>= 1) {
    if (l < st) red[l] += red[l + st];
    __syncthreads();
  }
  if (l == 0) {
    float msq = red[0];
    float sumq = 0.f;
    for (int i = 0; i < D; ++i) sumq += ick[i];
    float bsq = 0.f;
    for (int i = 0; i < D; ++i) bsq = fmaf(b[i], b[i], bsq);
    eSa[k] = alphas[k] + sumq - 0.5f * bsq;
    float g = wg[0], mm = wm[0];
    wwk[k] = 0.5f * g * g * msq - mm * sumq;
  }
  __syncthreads();

  int s = k >> 4, krow = k & 15;
  for (int u = l; u < NCHUNK * 4; u += 64) {
    int c = u >> 2, g = u & 3;
    unsigned int hw[4] = {0, 0, 0, 0};
    for (int j2 = 0; j2 < 8; ++j2) {
      int f = c * 32 + g * 8 + j2;
      float wv2;
      if (f < 32) wv2 = v[f];
      else if (f < NFEAT) wv2 = At[f - 32];
      else wv2 = 0.0f;
      hw[j2 >> 1] |= ((unsigned int)f2bf(wv2)) << (16 * (j2 & 1));
    }
    Whi[(s * NCHUNK + c) * 64 + g * 16 + krow] = make_uint4(hw[0], hw[1], hw[2], hw[3]);
  }

  // ---- block 0: wave-parallel tail constant (lgamma, lse(alphas), CONST) ----
  if (k == 0) {
    float a = alphas[l];
    float m = a;
#pragma unroll
    for (int off = 32; off > 0; off >>= 1) m = fmaxf(m, __shfl_xor(m, off));
    double e = exp((double)(a - m));
#pragma unroll
    for (int off = 32; off > 0; off >>= 1) e += __shfl_xor(e, off);
    double lse_a = (double)m + log(e);

    double nw = (double)D + (double)wm[0] + 1.0;
    double lg = (l < D) ? lgamma(0.5 * nw + (1.0 - (double)(l + 1)) * 0.5) : 0.0;
#pragma unroll
    for (int off = 32; off > 0; off >>= 1) lg += __shfl_xor(lg, off);

    if (l == 0) {
      double mg = (D * (D - 1) / 4.0) * log(M_PI) + lg;
      double gg = (double)wg[0];
      double C = nw * (double)D * log(gg / sqrt(2.0));
      double CONST = -(double)N * D * 0.5 * log(2.0 * M_PI);
      tailc[0] = CONST - (double)N * lse_a - (double)K_COMP * (C - mg);
    }
  }
}

// ------------------- main: R15 hot path + pure-add fused tail -------------------
__global__ __launch_bounds__(256, 4) void gmm_main(
    const float* __restrict__ x, const int4* __restrict__ Whi,
    const float* __restrict__ eSa, const float* __restrict__ wwk,
    const double* __restrict__ tailc, int N,
    float* __restrict__ partials, unsigned int* __restrict__ counter,
    float* __restrict__ out)
{
  __shared__ __align__(16) char phi[PTS_PER_BLK * ROWB];
  __shared__ float xs[PTS_PER_BLK][XSTRIDE];
  __shared__ float lmm[4][PTS_PER_BLK];
  __shared__ float lss[4][PTS_PER_BLK];
  __shared__ unsigned int isLastS;

  int tid = threadIdx.x;
  int lane = tid & 63;
  int slice = __builtin_amdgcn_readfirstlane(tid >> 6);
  int g = lane >> 4, n16 = lane & 15;

  // ---- phase 0: coalesced x-tile load (block tile = contiguous 4KB span) ----
  {
    size_t fidx = (size_t)blockIdx.x * (PTS_PER_BLK * D) + tid * 4;
    size_t maxf = (size_t)N * D - 4;
    if (fidx > maxf) fidx = maxf;
    float4 v = *reinterpret_cast<const float4*>(x + fidx);
    int r = tid >> 3, c = (tid & 7) * 4;
    xs[r][c + 0] = v.x; xs[r][c + 1] = v.y; xs[r][c + 2] = v.z; xs[r][c + 3] = v.w;
  }
  __syncthreads();

  // ---- phase 1: feature generation straight from LDS ----
  {
    int ptl = tid & 31;
    int h = tid >> 5;
    const float* xrow = &xs[ptl][0];
    char* row = phi + (size_t)ptl * ROWB;
    switch (h) {
      case 0: gen72<  0>(xrow, row, std::make_index_sequence<18>{}); break;
      case 1: gen72< 72>(xrow, row, std::make_index_sequence<18>{}); break;
      case 2: gen72<144>(xrow, row, std::make_index_sequence<18>{}); break;
      case 3: gen72<216>(xrow, row, std::make_index_sequence<18>{}); break;
      case 4: gen72<288>(xrow, row, std::make_index_sequence<18>{}); break;
      case 5: gen72<360>(xrow, row, std::make_index_sequence<18>{}); break;
      case 6: gen72<432>(xrow, row, std::make_index_sequence<18>{}); break;
      case 7: gen72<504>(xrow, row, std::make_index_sequence<18>{}); break;
    }
  }
  __syncthreads();

  // ---- phase 2: GEMM inner[k, n] = W @ phi, one k-slice (16 k) per wave ----
  v4f acc0 = {0.f, 0.f, 0.f, 0.f};
  v4f acc1 = {0.f, 0.f, 0.f, 0.f};
  const char* brow0 = phi + (size_t)(0 * 16 + n16) * ROWB + g * 16;
  const char* brow1 = phi + (size_t)(1 * 16 + n16) * ROWB + g * 16;
  const int4* wp = Whi + slice * NCHUNK * 64 + lane;

  int4 ah = wp[0];
#pragma unroll
  for (int c = 0; c < NCHUNK; ++c) {
    int4 ah_n;
    if (c + 1 < NCHUNK) ah_n = wp[(c + 1) * 64];
    int4 b0 = *reinterpret_cast<const int4*>(brow0 + c * 64);
    int4 b1 = *reinterpret_cast<const int4*>(brow1 + c * 64);
    v8s ahs = asv8(ah), b0s = asv8(b0), b1s = asv8(b1);
    acc0 = __builtin_amdgcn_mfma_f32_16x16x32_bf16(ahs, b0s, acc0, 0, 0, 0);
    acc1 = __builtin_amdgcn_mfma_f32_16x16x32_bf16(ahs, b1s, acc1, 0, 0, 0);
    ah = ah_n;
  }

  // ---- epilogue: add f32 constant eS[k], per-lane lse over 4 k, merge lane-groups ----
  float4 es = reinterpret_cast<const float4*>(eSa)[slice * 4 + g];
  acc0.x += es.x; acc0.y += es.y; acc0.z += es.z; acc0.w += es.w;
  acc1.x += es.x; acc1.y += es.y; acc1.z += es.z; acc1.w += es.w;

#pragma unroll
  for (int G = 0; G < 2; ++G) {
    v4f a = (G == 0) ? acc0 : acc1;
    float m = fmaxf(fmaxf(a.x, a.y), fmaxf(a.z, a.w));
    float sv = __expf(a.x - m) + __expf(a.y - m) + __expf(a.z - m) + __expf(a.w - m);
#pragma unroll
    for (int off = 16; off <= 32; off <<= 1) {
      float mo = __shfl_xor(m, off);
      float so = __shfl_xor(sv, off);
      float mn = fmaxf(m, mo);
      sv = sv * __expf(m - mn) + so * __expf(mo - mn);
      m = mn;
    }
    if (lane < 16) { lmm[slice][G * 16 + lane] = m; lss[slice][G * 16 + lane] = sv; }
  }
  __syncthreads();

  // ---- in-block merge of the 4 k-slices + block reduction -> 1 float ----
  if (tid < PTS_PER_BLK) {
    float m0 = lmm[0][tid], m1 = lmm[1][tid], m2 = lmm[2][tid], m3 = lmm[3][tid];
    float mm = fmaxf(fmaxf(m0, m1), fmaxf(m2, m3));
    float ss = lss[0][tid] * __expf(m0 - mm) + lss[1][tid] * __expf(m1 - mm)
             + lss[2][tid] * __expf(m2 - mm) + lss[3][tid] * __expf(m3 - mm);
    int n = blockIdx.x * PTS_PER_BLK + tid;
    float lse = (n < N) ? (mm + __logf(ss)) : 0.f;
#pragma unroll
    for (int off = 16; off > 0; off >>= 1) lse += __shfl_down(lse, off);
    if (tid == 0) partials[blockIdx.x] = lse;
  }

  // ---- last-block-done fused tail: pure f64 adds (no lgamma/exp => regalloc-safe) ----
  if (tid == 0) {
    __threadfence();
    isLastS = (atomicAdd(counter, 1u) == gridDim.x - 1) ? 1u : 0u;
  }
  __syncthreads();
  if (isLastS == 0) return;
  __threadfence();

  {
    int nblocks = gridDim.x;
    double* sd = reinterpret_cast<double*>(phi);   // reuse dead LDS
    volatile const float* vp = partials;
    double acc = 0.0;
    for (int i = tid; i < nblocks; i += 256) acc += (double)vp[i];
    if (tid < K_COMP) acc += (double)wwk[tid];
    sd[tid] = acc;
    __syncthreads();
    for (int st = 128; st > 0; st >>= 1) {
      if (tid < st) sd[tid] += sd[tid + st];
      __syncthreads();
    }
    if (tid == 0) out[0] = (float)(sd[0] + tailc[0]);
  }
}

extern "C" void kernel_launch(void* const* d_in, const int* in_sizes, int n_in,
                              void* d_out, int out_size, void* d_ws, size_t ws_size,
                              hipStream_t stream)
{
  const float* alphas = (const float*)d_in[0];
  const float* means  = (const float*)d_in[1];
  const float* icf    = (const float*)d_in[2];
  const float* x      = (const float*)d_in[3];
  const float* wg     = (const float*)d_in[4];
  const float* wm     = (const float*)d_in[5];
  float* out = (float*)d_out;

  int N = in_sizes[3] / D;
  int npblk = (N + PTS_PER_BLK - 1) / PTS_PER_BLK;   // 1563

  char* wsb = (char*)d_ws;
  const size_t WBYTES = (size_t)4 * NCHUNK * 64 * 16; // 73728
  uint4*  Whi = (uint4*)wsb;
  float*  eSa = (float*)(wsb + WBYTES);               // 64 f
  float*  wwk = eSa + K_COMP;                         // 64 f
  double* tailc = (double*)(wsb + WBYTES + 512);      // 8-byte aligned
  float*  partials = (float*)(wsb + WBYTES + 512 + 8);
  unsigned int* counter = (unsigned int*)(partials + npblk);

  hipMemsetAsync(counter, 0, sizeof(unsigned int), stream);
  gmm_prep<<<K_COMP, 64, 0, stream>>>(alphas, means, icf, wg, wm, N, Whi, eSa, wwk, tailc);
  gmm_main<<<npblk, 256, 0, stream>>>(x, (const int4*)Whi, eSa, wwk, tailc, N,
                                      partials, counter, out);
}

// Round 17
// 40.415 us; speedup vs baseline: 1.6994x; 1.6994x over previous
//
#include <hip/hip_runtime.h>
#include <hip/hip_bf16.h>
#include <math.h>
#include <utility>

#define K_COMP 64
#define D 32
#define NTRIL 496
#define ICF_COLS 528
#define NPAIR 528            // i<=j pairs
#define NFEAT 560            // 32 linear + 528 pair (constant term in epilogue)
#define NCHUNK 18            // 576 = 18*32 padded features
#define PTS_PER_BLK 32
#define ROWB 1168            // phi row stride bytes
#define XSTRIDE 33           // xs row stride floats: 33 mod 32 = 1 -> conflict-free rows

typedef __attribute__((ext_vector_type(8))) short v8s;
typedef __attribute__((ext_vector_type(4))) float v4f;

__device__ __forceinline__ unsigned short f2bf(float f) {
  unsigned int u = __float_as_uint(f);
  unsigned int r = (u + 0x7FFFu + ((u >> 16) & 1u)) >> 16;
  return (unsigned short)r;
}
__device__ __forceinline__ v8s asv8(int4 v) {
  union { int4 i; v8s s; } u; u.i = v; return u.s;
}

// pair enumeration t -> (i,j), i<=j, i ascending, j from i..31
constexpr int pr_i(int t) { int i = 0; while (t >= D - i) { t -= D - i; ++i; } return i; }
constexpr int pr_j(int t) { int i = 0; while (t >= D - i) { t -= D - i; ++i; } return i + t; }

// feature read DIRECTLY from LDS row (compile-time offsets; no register array)
template<int F> __device__ __forceinline__ float featL(const float* __restrict__ xrow) {
  if constexpr (F < 32) return xrow[F];
  else if constexpr (F < NFEAT) {
    constexpr int t = F - 32, i = pr_i(t), j = pr_j(t);
    return xrow[i] * xrow[j];
  } else return 0.0f;
}

// 4 features -> 2x v_cvt_pk_bf16_f32 -> one 8B LDS write
template<int F0> __device__ __forceinline__ void write4L(const float* __restrict__ xrow, char* row) {
  __hip_bfloat162 pa = __float22bfloat162_rn(make_float2(featL<F0+0>(xrow), featL<F0+1>(xrow)));
  __hip_bfloat162 pb = __float22bfloat162_rn(make_float2(featL<F0+2>(xrow), featL<F0+3>(xrow)));
  union { __hip_bfloat162 h2; unsigned u; } ua, ub;
  ua.h2 = pa; ub.h2 = pb;
  *reinterpret_cast<uint2*>(row + (size_t)F0 * 2) = make_uint2(ua.u, ub.u);
}
template<int BASE, size_t... Qs> __device__ __forceinline__
void gen72(const float* __restrict__ xrow, char* row, std::index_sequence<Qs...>) {
  (write4L<BASE + 4 * (int)Qs>(xrow, row), ...);
}

// ------------------- prep: one block per component k (R15, unchanged) -------------------
__global__ __launch_bounds__(64) void gmm_prep(
    const float* __restrict__ alphas, const float* __restrict__ means,
    const float* __restrict__ icf, const float* __restrict__ wg,
    const float* __restrict__ wm,
    uint4* __restrict__ Whi, float* __restrict__ eSa, float* __restrict__ wwk)
{
  int k = blockIdx.x;
  int l = threadIdx.x;
  __shared__ float M[D][D + 1];
  __shared__ float mu[D], b[D], v[D];
  __shared__ float At[NPAIR];
  __shared__ float red[64];

  const float* ick = icf + (size_t)k * ICF_COLS;

  if (l < D) {
    mu[l] = means[k * D + l];
    float q = __expf(ick[l]);
    for (int c = 0; c < D; ++c) {
      float val;
      if (c < l) { int off = c * 31 - c * (c - 1) / 2; val = ick[D + off + (l - c - 1)]; }
      else if (c == l) val = q;
      else val = 0.0f;
      M[l][c] = val;
    }
  }
  __syncthreads();
  if (l < D) {
    float acc = 0.f;
    for (int c = 0; c < D; ++c) acc = fmaf(M[l][c], mu[c], acc);
    b[l] = acc;
  }
  __syncthreads();
  if (l < D) {
    float acc = 0.f;
    for (int r = 0; r < D; ++r) acc = fmaf(M[r][l], b[r], acc);
    v[l] = acc;
  }
  for (int t = l; t < NPAIR; t += 64) {
    int tt = t, i = 0;
    while (tt >= D - i) { tt -= D - i; ++i; }
    int j = i + tt;
    float acc = 0.f;
    for (int r = 0; r < D; ++r) acc = fmaf(M[r][i], M[r][j], acc);
    At[t] = (i == j) ? -0.5f * acc : -acc;
  }
  float part = 0.f;
  for (int e = l; e < D * D; e += 64) {
    float mv = M[e / D][e % D];
    part = fmaf(mv, mv, part);
  }
  red[l] = part;
  __syncthreads();
  for (int st = 32; st > 0; st >>= 1) {
    if (l < st) red[l] += red[l + st];
    __syncthreads();
  }
  if (l == 0) {
    float msq = red[0];
    float sumq = 0.f;
    for (int i = 0; i < D; ++i) sumq += ick[i];
    float bsq = 0.f;
    for (int i = 0; i < D; ++i) bsq = fmaf(b[i], b[i], bsq);
    eSa[k] = alphas[k] + sumq - 0.5f * bsq;
    float g = wg[0], mm = wm[0];
    wwk[k] = 0.5f * g * g * msq - mm * sumq;
  }
  __syncthreads();

  int s = k >> 4, krow = k & 15;
  for (int u = l; u < NCHUNK * 4; u += 64) {
    int c = u >> 2, g = u & 3;
    unsigned int hw[4] = {0, 0, 0, 0};
    for (int j2 = 0; j2 < 8; ++j2) {
      int f = c * 32 + g * 8 + j2;
      float wv2;
      if (f < 32) wv2 = v[f];
      else if (f < NFEAT) wv2 = At[f - 32];
      else wv2 = 0.0f;
      hw[j2 >> 1] |= ((unsigned int)f2bf(wv2)) << (16 * (j2 & 1));
    }
    Whi[(s * NCHUNK + c) * 64 + g * 16 + krow] = make_uint4(hw[0], hw[1], hw[2], hw[3]);
  }
}

// ------------------- main: R15 champion, byte-identical -------------------
__global__ __launch_bounds__(256, 4) void gmm_main(
    const float* __restrict__ x, const int4* __restrict__ Whi,
    const float* __restrict__ eSa, int N, float* __restrict__ partials)
{
  __shared__ __align__(16) char phi[PTS_PER_BLK * ROWB];
  __shared__ float xs[PTS_PER_BLK][XSTRIDE];
  __shared__ float lmm[4][PTS_PER_BLK];
  __shared__ float lss[4][PTS_PER_BLK];

  int tid = threadIdx.x;
  int lane = tid & 63;
  int slice = __builtin_amdgcn_readfirstlane(tid >> 6);
  int g = lane >> 4, n16 = lane & 15;

  // ---- phase 0: coalesced x-tile load (block tile = contiguous 4KB span) ----
  {
    size_t fidx = (size_t)blockIdx.x * (PTS_PER_BLK * D) + tid * 4;
    size_t maxf = (size_t)N * D - 4;
    if (fidx > maxf) fidx = maxf;
    float4 v = *reinterpret_cast<const float4*>(x + fidx);
    int r = tid >> 3, c = (tid & 7) * 4;
    xs[r][c + 0] = v.x; xs[r][c + 1] = v.y; xs[r][c + 2] = v.z; xs[r][c + 3] = v.w;
  }
  __syncthreads();

  // ---- phase 1: feature generation straight from LDS ----
  {
    int ptl = tid & 31;
    int h = tid >> 5;
    const float* xrow = &xs[ptl][0];
    char* row = phi + (size_t)ptl * ROWB;
    switch (h) {
      case 0: gen72<  0>(xrow, row, std::make_index_sequence<18>{}); break;
      case 1: gen72< 72>(xrow, row, std::make_index_sequence<18>{}); break;
      case 2: gen72<144>(xrow, row, std::make_index_sequence<18>{}); break;
      case 3: gen72<216>(xrow, row, std::make_index_sequence<18>{}); break;
      case 4: gen72<288>(xrow, row, std::make_index_sequence<18>{}); break;
      case 5: gen72<360>(xrow, row, std::make_index_sequence<18>{}); break;
      case 6: gen72<432>(xrow, row, std::make_index_sequence<18>{}); break;
      case 7: gen72<504>(xrow, row, std::make_index_sequence<18>{}); break;
    }
  }
  __syncthreads();

  // ---- phase 2: GEMM inner[k, n] = W @ phi, one k-slice (16 k) per wave ----
  v4f acc0 = {0.f, 0.f, 0.f, 0.f};
  v4f acc1 = {0.f, 0.f, 0.f, 0.f};
  const char* brow0 = phi + (size_t)(0 * 16 + n16) * ROWB + g * 16;
  const char* brow1 = phi + (size_t)(1 * 16 + n16) * ROWB + g * 16;
  const int4* wp = Whi + slice * NCHUNK * 64 + lane;

  int4 ah = wp[0];
#pragma unroll
  for (int c = 0; c < NCHUNK; ++c) {
    int4 ah_n;
    if (c + 1 < NCHUNK) ah_n = wp[(c + 1) * 64];
    int4 b0 = *reinterpret_cast<const int4*>(brow0 + c * 64);
    int4 b1 = *reinterpret_cast<const int4*>(brow1 + c * 64);
    v8s ahs = asv8(ah), b0s = asv8(b0), b1s = asv8(b1);
    acc0 = __builtin_amdgcn_mfma_f32_16x16x32_bf16(ahs, b0s, acc0, 0, 0, 0);
    acc1 = __builtin_amdgcn_mfma_f32_16x16x32_bf16(ahs, b1s, acc1, 0, 0, 0);
    ah = ah_n;
  }

  // ---- epilogue: add f32 constant eS[k], per-lane lse over 4 k, merge lane-groups ----
  float4 es = reinterpret_cast<const float4*>(eSa)[slice * 4 + g];
  acc0.x += es.x; acc0.y += es.y; acc0.z += es.z; acc0.w += es.w;
  acc1.x += es.x; acc1.y += es.y; acc1.z += es.z; acc1.w += es.w;

#pragma unroll
  for (int G = 0; G < 2; ++G) {
    v4f a = (G == 0) ? acc0 : acc1;
    float m = fmaxf(fmaxf(a.x, a.y), fmaxf(a.z, a.w));
    float sv = __expf(a.x - m) + __expf(a.y - m) + __expf(a.z - m) + __expf(a.w - m);
#pragma unroll
    for (int off = 16; off <= 32; off <<= 1) {
      float mo = __shfl_xor(m, off);
      float so = __shfl_xor(sv, off);
      float mn = fmaxf(m, mo);
      sv = sv * __expf(m - mn) + so * __expf(mo - mn);
      m = mn;
    }
    if (lane < 16) { lmm[slice][G * 16 + lane] = m; lss[slice][G * 16 + lane] = sv; }
  }
  __syncthreads();

  // ---- in-block merge of the 4 k-slices + block reduction -> 1 float ----
  if (tid < PTS_PER_BLK) {
    float m0 = lmm[0][tid], m1 = lmm[1][tid], m2 = lmm[2][tid], m3 = lmm[3][tid];
    float mm = fmaxf(fmaxf(m0, m1), fmaxf(m2, m3));
    float ss = lss[0][tid] * __expf(m0 - mm) + lss[1][tid] * __expf(m1 - mm)
             + lss[2][tid] * __expf(m2 - mm) + lss[3][tid] * __expf(m3 - mm);
    int n = blockIdx.x * PTS_PER_BLK + tid;
    float lse = (n < N) ? (mm + __logf(ss)) : 0.f;
#pragma unroll
    for (int off = 16; off > 0; off >>= 1) lse += __shfl_down(lse, off);
    if (tid == 0) partials[blockIdx.x] = lse;
  }
}

// ------- final: cheap tail — 2 lgammas + log ladder, float alpha-lse, f64 sums -------
__global__ __launch_bounds__(256) void gmm_final(
    const float* __restrict__ wwk, const float* __restrict__ partials, int nblocks,
    const float* __restrict__ alphas, const float* __restrict__ wg,
    const float* __restrict__ wm, int N, float* __restrict__ out)
{
  int tid = threadIdx.x;
  __shared__ double sd[256];
  __shared__ float samax;
  __shared__ double s_slse, s_sa, s_ow;

  // 1) sum of per-block lse partials (f64 adds, deterministic tree)
  double acc = 0.0;
  for (int i = tid; i < nblocks; i += 256) acc += (double)partials[i];
  sd[tid] = acc;
  __syncthreads();
  for (int st = 128; st > 0; st >>= 1) {
    if (tid < st) sd[tid] += sd[tid + st];
    __syncthreads();
  }
  if (tid == 0) s_slse = sd[0];
  __syncthreads();

  // 2) max(alphas) via wave 0 shuffle
  if (tid < 64) {
    float m = alphas[tid];
#pragma unroll
    for (int off = 32; off > 0; off >>= 1) m = fmaxf(m, __shfl_xor(m, off));
    if (tid == 0) samax = m;
  }
  __syncthreads();

  // 3) sum exp(alphas - amax) via FLOAT HW exp (error ~1e-7 rel, harmless here)
  sd[tid] = (tid < K_COMP) ? (double)__expf(alphas[tid] - samax) : 0.0;
  __syncthreads();
  for (int st = 128; st > 0; st >>= 1) {
    if (tid < st) sd[tid] += sd[tid + st];
    __syncthreads();
  }
  if (tid == 0) s_sa = sd[0];
  __syncthreads();

  // 4) sum wwk (f64 adds)
  sd[tid] = (tid < K_COMP) ? (double)wwk[tid] : 0.0;
  __syncthreads();
  for (int st = 128; st > 0; st >>= 1) {
    if (tid < st) sd[tid] += sd[tid + st];
    __syncthreads();
  }
  if (tid == 0) s_ow = sd[0];
  __syncthreads();

  // 5) multigammaln via ladder: sum_{k=0..15} lgamma(a-k) = 16*lgamma(a) - sum_{k=1..15}(16-k)*log(a-k)
  double nw = (double)D + (double)wm[0] + 1.0;
  double a  = 0.5 * nw;          // 17.0 for wm=1
  double bh = a - 0.5;
  double contrib = 0.0;
  if (tid == 0)      contrib = 16.0 * lgamma(a);
  else if (tid == 1) contrib = 16.0 * lgamma(bh);
  else if (tid >= 2 && tid < 17)  { int k = tid - 1;  contrib = -(double)(16 - k) * log(a  - (double)k); }
  else if (tid >= 17 && tid < 32) { int k = tid - 16; contrib = -(double)(16 - k) * log(bh - (double)k); }
  sd[tid] = contrib;
  __syncthreads();
  for (int st = 128; st > 0; st >>= 1) {
    if (tid < st) sd[tid] += sd[tid + st];
    __syncthreads();
  }

  if (tid == 0) {
    double mg = (D * (D - 1) / 4.0) * log(M_PI) + sd[0];
    double lse_a = (double)samax + log(s_sa);
    double g = (double)wg[0];
    double C = nw * (double)D * log(g / sqrt(2.0));
    double CONST = -(double)N * D * 0.5 * log(2.0 * M_PI);
    double prior = s_ow - (double)K_COMP * (C - mg);
    out[0] = (float)(CONST + s_slse - (double)N * lse_a + prior);
  }
}

extern "C" void kernel_launch(void* const* d_in, const int* in_sizes, int n_in,
                              void* d_out, int out_size, void* d_ws, size_t ws_size,
                              hipStream_t stream)
{
  const float* alphas = (const float*)d_in[0];
  const float* means  = (const float*)d_in[1];
  const float* icf    = (const float*)d_in[2];
  const float* x      = (const float*)d_in[3];
  const float* wg     = (const float*)d_in[4];
  const float* wm     = (const float*)d_in[5];
  float* out = (float*)d_out;

  int N = in_sizes[3] / D;
  int npblk = (N + PTS_PER_BLK - 1) / PTS_PER_BLK;   // 1563

  char* wsb = (char*)d_ws;
  const size_t WBYTES = (size_t)4 * NCHUNK * 64 * 16; // 73728
  uint4* Whi = (uint4*)wsb;
  float* eSa = (float*)(wsb + WBYTES);
  float* wwk = eSa + K_COMP;
  float* partials = wwk + K_COMP;

  gmm_prep<<<K_COMP, 64, 0, stream>>>(alphas, means, icf, wg, wm, Whi, eSa, wwk);
  gmm_main<<<npblk, 256, 0, stream>>>(x, (const int4*)Whi, eSa, N, partials);
  gmm_final<<<1, 256, 0, stream>>>(wwk, partials, npblk, alphas, wg, wm, N, out);
}